// Round 6
// baseline (210.893 us; speedup 1.0000x reference)
//
#include <hip/hip_runtime.h>
#include <stdint.h>

// ---------------- problem constants (fixed by setup_inputs) ----------------
#define G       69
#define BATCH   8
// sparse_shape (Z,Y,X) = (32,512,512), window (12,12,32), SHIFT=true
// mwx = 44, mwy = 44, mwz = 2
#define MPS     3872        // 44*44*2
#define VOL     4608        // 12*12*32
// max key = 142,737,407 < 2^28
#define NBUK    1089        // buckets per map: key>>17
#define NB2     2178        // both maps
#define B_WORDS 4096        // 2^17 bits per bucket / 32
#define NQUAD   1024        // B_WORDS/4
#define NBLK    256         // chunks for the counting sort
#define MAXBUK  4096        // blkOf capacity (expected max bucket ~2050)

// segment-order permutation: p -> block = (p%32)*8 + p/32  (groups XCD-mates)
#define PERM(p)  ((((p) & 31) << 3) + ((p) >> 5))

// ctrl layout (int32 indices)
#define C_COUNTS 0   // [8]
#define C_BS     8   // [9]
#define C_CP     17  // [8]
#define C_BSP    25  // [9]

__device__ __forceinline__ void keys_from_coord(int4 c, unsigned& kx, unsigned& ky) {
    int b  = c.x;
    int zz = c.y + 16;   // z + win_z/2
    int yy = c.z + 6;    // y + win_y/2
    int xx = c.w + 6;    // x + win_x/2
    int wx = xx / 12, cx = xx - wx*12;
    int wy = yy / 12, cy = yy - wy*12;
    int wz = zz >> 5, cz = zz & 31;
    int bwx = b*MPS + wx*88 + wy*2 + wz;   // mwy*mwz = 88
    int bwy = b*MPS + wy*88 + wx*2 + wz;   // mwx*mwz = 88
    kx = (unsigned)(bwx*VOL + cx*384 + cy*32 + cz);  // win_y*win_z = 384
    ky = (unsigned)(bwy*VOL + cy*384 + cx*32 + cz);  // win_x*win_z = 384
}

// ---------------- K1: per-chunk LDS bucket histogram + per-block batch counts ----------------
__global__ void hist_kernel(const int4* __restrict__ coords, int N, int chunk,
                            unsigned* __restrict__ histMat, int* __restrict__ batchMat) {
    __shared__ unsigned h[NB2];
    __shared__ int hb[BATCH];
    int t = threadIdx.x, blk = blockIdx.x;
    for (int k = t; k < NB2; k += 256) h[k] = 0;
    if (t < BATCH) hb[t] = 0;
    __syncthreads();
    int start = blk * chunk;
    int end   = min(start + chunk, N);
    int c0=0,c1=0,c2=0,c3=0,c4=0,c5=0,c6=0,c7=0;
    for (int i = start + t; i < end; i += 256) {
        int4 c = coords[i];
        int b = c.x;
        c0 += (b==0); c1 += (b==1); c2 += (b==2); c3 += (b==3);
        c4 += (b==4); c5 += (b==5); c6 += (b==6); c7 += (b==7);
        unsigned kx, ky;
        keys_from_coord(c, kx, ky);
        atomicAdd(&h[kx >> 17], 1u);
        atomicAdd(&h[NBUK + (ky >> 17)], 1u);
    }
    atomicAdd(&hb[0],c0); atomicAdd(&hb[1],c1); atomicAdd(&hb[2],c2); atomicAdd(&hb[3],c3);
    atomicAdd(&hb[4],c4); atomicAdd(&hb[5],c5); atomicAdd(&hb[6],c6); atomicAdd(&hb[7],c7);
    __syncthreads();
    for (int k = t; k < NB2; k += 256) histMat[(size_t)blk * NB2 + k] = h[k];
    if (t < BATCH) batchMat[blk * BATCH + t] = hb[t];
}

// ---------------- K2a: per-bucket exclusive scan over blocks in XCD-grouped order ----------------
__global__ void colscan_kernel(unsigned* __restrict__ histMat, unsigned* __restrict__ totals,
                               unsigned* __restrict__ colT) {
    int k = blockIdx.x * blockDim.x + threadIdx.x;
    if (k >= NB2) return;
    unsigned run = 0;
    for (int p0 = 0; p0 < NBLK; p0 += 8) {
        unsigned v[8]; int bb[8];
        #pragma unroll
        for (int u = 0; u < 8; u++) { bb[u] = PERM(p0+u); v[u] = histMat[(size_t)bb[u] * NB2 + k]; }
        #pragma unroll
        for (int u = 0; u < 8; u++) {
            histMat[(size_t)bb[u] * NB2 + k] = run;
            colT[(size_t)k * NBLK + (p0+u)]  = run;
            run += v[u];
        }
    }
    totals[k] = run;
}

// ---------------- K2b: batch counts + prefixes; bucket-total scan -> recStart ----------------
__global__ void scan_kernel(int* __restrict__ ctrl, const int* __restrict__ batchMat,
                            const unsigned* __restrict__ totals, unsigned* __restrict__ recStart) {
    int t = threadIdx.x;
    if (t < BATCH) {
        int s = 0;
        for (int blk = 0; blk < NBLK; blk++) s += batchMat[blk * BATCH + t];
        ctrl[C_COUNTS + t] = s;
    }
    __syncthreads();
    if (t == 0) {
        int bs = 0, bsp = 0;
        ctrl[C_BS] = 0; ctrl[C_BSP] = 0;
        for (int b = 0; b < BATCH; b++) {
            int n  = ctrl[C_COUNTS + b];
            int np = ((n + G - 1) / G) * G;
            ctrl[C_CP + b] = np;
            bs += n; bsp += np;
            ctrl[C_BS + b + 1]  = bs;
            ctrl[C_BSP + b + 1] = bsp;
        }
    }
    __shared__ unsigned sc[256];
    __shared__ unsigned s_run;
    if (t == 0) s_run = 0;
    __syncthreads();
    for (int base = 0; base < NB2; base += 256) {
        unsigned v = (base + t < NB2) ? totals[base + t] : 0;
        sc[t] = v; __syncthreads();
        for (int d = 1; d < 256; d <<= 1) {
            unsigned u = (t >= d) ? sc[t - d] : 0;
            __syncthreads();
            sc[t] += u;
            __syncthreads();
        }
        unsigned excl = s_run + sc[t] - v;
        if (base + t < NB2) recStart[base + t] = excl;
        unsigned tot = sc[255];
        __syncthreads();
        if (t == 0) s_run += tot;
        __syncthreads();
    }
    if (t == 0) recStart[NB2] = s_run;   // == 2N
}

// ---------------- K3: binning (packed 4B records) + win2flat + fused flat2win ----------------
__global__ void bin_kernel(const int4* __restrict__ coords, int N, int chunk,
                           int Np, int chunkP,
                           const int* __restrict__ ctrl,
                           const unsigned* __restrict__ recStart,
                           const unsigned* __restrict__ histMat,
                           unsigned* __restrict__ rec,
                           int* __restrict__ win2flat,
                           int* __restrict__ f2w) {
    __shared__ unsigned cur[NB2];
    __shared__ int s_bs[BATCH+1], s_bsp[BATCH+1], s_cnt[BATCH], s_cp[BATCH];
    int t = threadIdx.x, blk = blockIdx.x;
    if (t < BATCH)   { s_cnt[t] = ctrl[C_COUNTS+t]; s_cp[t] = ctrl[C_CP+t]; }
    if (t < BATCH+1) { s_bs[t]  = ctrl[C_BS+t];     s_bsp[t] = ctrl[C_BSP+t]; }
    for (int k = t; k < NB2; k += 256)
        cur[k] = recStart[k] + histMat[(size_t)blk * NB2 + k];
    __syncthreads();
    int start = blk * chunk;
    int end   = min(start + chunk, N);
    for (int i = start + t; i < end; i += 256) {
        int4 c = coords[i];
        win2flat[i] = i + (s_bsp[c.x] - s_bs[c.x]);
        unsigned kx, ky;
        keys_from_coord(c, kx, ky);
        unsigned off = (unsigned)(i - start);
        unsigned px = atomicAdd(&cur[kx >> 17], 1u);
        rec[px] = ((kx & 131071u) << 15) | off;
        unsigned py = atomicAdd(&cur[NBUK + (ky >> 17)], 1u);
        rec[py] = ((ky & 131071u) << 15) | off;
    }
    // fused flat2win over this block's slice of [0, Np)
    int pstart = blk * chunkP;
    int pend   = min(pstart + chunkP, Np);
    for (int j = pstart + t; j < pend; j += 256) {
        int b = 0;
        #pragma unroll
        for (int k = 1; k < BATCH; k++) b += (j >= s_bsp[k]);
        int off  = s_bsp[b] - s_bs[b];
        int num  = s_cnt[b], nump = s_cp[b];
        int r    = num % G;
        int tail_start = (num != nump) ? (s_bsp[b+1] - G + r) : s_bsp[b+1];
        int v;
        if (j < tail_start)       v = j - off;
        else if (nump != G)       v = j - G - off;
        else { int tt = j - tail_start; int m = num > 0 ? num : 1; v = s_bs[b] + tt % m; }
        f2w[j] = v;
    }
}

// ---------------- K5: per-bucket LDS bitmap rank + scatter (conflict-free quad scan) ----------------
__global__ void rank_kernel(const unsigned* __restrict__ rec,
                            const unsigned* __restrict__ recStart,
                            const unsigned* __restrict__ colT,
                            int N, int chunk,
                            int* __restrict__ xmap, int* __restrict__ ymap) {
    int b = blockIdx.x;                      // 0..NB2-1
    unsigned start = recStart[b], end = recStart[b+1];
    unsigned sz = end - start;
    int map = (b >= NBUK);
    __shared__ unsigned bits[B_WORDS];       // 16 KB
    __shared__ unsigned prefQ[NQUAD];        // 4 KB: exclusive prefix per 4-word quad
    __shared__ unsigned sc[256];
    __shared__ unsigned col[NBLK + 1];
    __shared__ uint8_t blkOf[MAXBUK];        // stores permuted index p
    int t = threadIdx.x;
    // zero bitmap: lane-contiguous b128, conflict-free
    uint4 z = make_uint4(0,0,0,0);
    #pragma unroll
    for (int r = 0; r < 4; r++) ((uint4*)bits)[r*256 + t] = z;
    col[t] = colT[(size_t)b * NBLK + t];
    if (t == 0) col[NBLK] = sz;
    __syncthreads();
    // expand col -> blkOf[pos] = p (segment index in permuted order)
    {
        unsigned lo = col[t], hi = min(col[t + 1], (unsigned)MAXBUK);
        for (unsigned p = lo; p < hi; p++) blkOf[p] = (uint8_t)t;
    }
    for (unsigned i = start + t; i < end; i += 256) {
        unsigned local = rec[i] >> 15;
        atomicOr(&bits[local >> 5], 1u << (local & 31));
    }
    __syncthreads();
    // quad sums, lane-contiguous b128 reads: round r covers quads r*256+t
    #pragma unroll
    for (int r = 0; r < 4; r++) {
        uint4 v = ((const uint4*)bits)[r*256 + t];
        prefQ[r*256 + t] = __popc(v.x) + __popc(v.y) + __popc(v.z) + __popc(v.w);
    }
    __syncthreads();
    // scan 1024 quad sums: thread t owns quads 4t..4t+3 (b128, lane-contiguous)
    uint4 q = ((const uint4*)prefQ)[t];
    unsigned tsum = q.x + q.y + q.z + q.w;
    sc[t] = tsum; __syncthreads();
    for (int d = 1; d < 256; d <<= 1) {
        unsigned u = (t >= d) ? sc[t - d] : 0;
        __syncthreads();
        sc[t] += u;
        __syncthreads();
    }
    unsigned e = sc[t] - tsum;
    uint4 pq;
    pq.x = e; pq.y = e + q.x; pq.z = e + q.x + q.y; pq.w = e + q.x + q.y + q.z;
    ((uint4*)prefQ)[t] = pq;
    __syncthreads();
    int* out = map ? ymap : xmap;
    unsigned rankBase = start - (map ? (unsigned)N : 0u);
    for (unsigned i = start + t; i < end; i += 256) {
        unsigned r = rec[i];
        unsigned local = r >> 15, off = r & 32767u;
        unsigned pos = i - start;
        unsigned p;
        if (pos < (unsigned)MAXBUK) p = blkOf[pos];
        else {                      // safety fallback (never expected)
            p = NBLK - 1;
            while (col[p] > pos) p--;
        }
        unsigned blk = (unsigned)PERM(p);
        unsigned idx = blk * (unsigned)chunk + off;
        unsigned wd = local >> 5, qi = wd >> 2, j = wd & 3, bt = local & 31;
        uint4 qw = ((const uint4*)bits)[qi];
        unsigned rank = rankBase + prefQ[qi];
        if (j > 0) rank += __popc(qw.x);
        if (j > 1) rank += __popc(qw.y);
        if (j > 2) rank += __popc(qw.z);
        unsigned wj = (j == 0) ? qw.x : (j == 1) ? qw.y : (j == 2) ? qw.z : qw.w;
        rank += __popc(wj & ((1u << bt) - 1u));
        out[rank] = (int)idx;
    }
}

// ---------------- launch ----------------
extern "C" void kernel_launch(void* const* d_in, const int* in_sizes, int n_in,
                              void* d_out, int out_size, void* d_ws, size_t ws_size,
                              hipStream_t stream) {
    const int* coords = (const int*)d_in[0];
    int N  = in_sizes[0] / 4;
    int Np = out_size - 3 * N;
    int chunk  = (N  + NBLK - 1) / NBLK;   // ~7817, fits 15 bits
    int chunkP = (Np + NBLK - 1) / NBLK;

    char* ws = (char*)d_ws;
    int*      ctrl     = (int*)(ws + 0);              // 256 B
    unsigned* totals   = (unsigned*)(ws + 256);       // 2178*4 -> ends 8968
    unsigned* recStart = (unsigned*)(ws + 8968);      // 2179*4 -> ends 17684
    int*      batchMat = (int*)(ws + 17684);          // 256*8*4 = 8192 -> ends 25876
    unsigned* histMat  = (unsigned*)(ws + 25888);     // 256*2178*4 -> ends 2,256,160
    unsigned* colT     = (unsigned*)(ws + 2256160);   // 2178*256*4 -> ends 4,486,432
    unsigned* rec      = (unsigned*)(ws + 4486432);   // 2N*4 B (~16 MB)

    int* out  = (int*)d_out;
    int* f2w  = out;
    int* w2f  = out + Np;
    int* xmap = out + Np + N;
    int* ymap = out + Np + 2*N;

    hist_kernel<<<NBLK, 256, 0, stream>>>((const int4*)coords, N, chunk, histMat, batchMat);
    colscan_kernel<<<(NB2 + 255)/256, 256, 0, stream>>>(histMat, totals, colT);
    scan_kernel<<<1, 256, 0, stream>>>(ctrl, batchMat, totals, recStart);
    bin_kernel<<<NBLK, 256, 0, stream>>>((const int4*)coords, N, chunk, Np, chunkP,
                                         ctrl, recStart, histMat, rec, w2f, f2w);
    rank_kernel<<<NB2, 256, 0, stream>>>(rec, recStart, colT, N, chunk, xmap, ymap);
}

// Round 7
// 191.061 us; speedup vs baseline: 1.1038x; 1.1038x over previous
//
#include <hip/hip_runtime.h>
#include <stdint.h>

// ---------------- problem constants (fixed by setup_inputs) ----------------
#define G       69
#define BATCH   8
// sparse_shape (Z,Y,X) = (32,512,512), window (12,12,32), SHIFT=true
// mwx = 44, mwy = 44, mwz = 2
#define MPS     3872        // 44*44*2
#define VOL     4608        // 12*12*32
// max key = 142,737,407 < 2^28
#define NBUK    1089        // buckets per map: key>>17
#define NB2     2178        // both maps
#define B_WORDS 4096        // 2^17 bits per bucket / 32
#define NQUAD   1024        // B_WORDS/4
#define NBLK    256         // chunks for the counting sort
#define MAXBUK  4096        // blkOf capacity (expected max bucket ~2050)

// ctrl layout (int32 indices)
#define C_COUNTS 0   // [8]
#define C_BS     8   // [9]
#define C_CP     17  // [8]
#define C_BSP    25  // [9]

__device__ __forceinline__ void keys_from_coord(int4 c, unsigned& kx, unsigned& ky) {
    int b  = c.x;
    int zz = c.y + 16;   // z + win_z/2
    int yy = c.z + 6;    // y + win_y/2
    int xx = c.w + 6;    // x + win_x/2
    int wx = xx / 12, cx = xx - wx*12;
    int wy = yy / 12, cy = yy - wy*12;
    int wz = zz >> 5, cz = zz & 31;
    int bwx = b*MPS + wx*88 + wy*2 + wz;   // mwy*mwz = 88
    int bwy = b*MPS + wy*88 + wx*2 + wz;   // mwx*mwz = 88
    kx = (unsigned)(bwx*VOL + cx*384 + cy*32 + cz);  // win_y*win_z = 384
    ky = (unsigned)(bwy*VOL + cy*384 + cx*32 + cz);  // win_x*win_z = 384
}

// ---------------- K1: per-chunk LDS bucket histogram + per-block batch counts ----------------
__global__ void hist_kernel(const int4* __restrict__ coords, int N, int chunk,
                            unsigned* __restrict__ histMat, int* __restrict__ batchMat) {
    __shared__ unsigned h[NB2];
    __shared__ int hb[BATCH];
    int t = threadIdx.x, blk = blockIdx.x;
    for (int k = t; k < NB2; k += 256) h[k] = 0;
    if (t < BATCH) hb[t] = 0;
    __syncthreads();
    int start = blk * chunk;
    int end   = min(start + chunk, N);
    int c0=0,c1=0,c2=0,c3=0,c4=0,c5=0,c6=0,c7=0;
    for (int i = start + t; i < end; i += 256) {
        int4 c = coords[i];
        int b = c.x;
        c0 += (b==0); c1 += (b==1); c2 += (b==2); c3 += (b==3);
        c4 += (b==4); c5 += (b==5); c6 += (b==6); c7 += (b==7);
        unsigned kx, ky;
        keys_from_coord(c, kx, ky);
        atomicAdd(&h[kx >> 17], 1u);
        atomicAdd(&h[NBUK + (ky >> 17)], 1u);
    }
    atomicAdd(&hb[0],c0); atomicAdd(&hb[1],c1); atomicAdd(&hb[2],c2); atomicAdd(&hb[3],c3);
    atomicAdd(&hb[4],c4); atomicAdd(&hb[5],c5); atomicAdd(&hb[6],c6); atomicAdd(&hb[7],c7);
    __syncthreads();
    for (int k = t; k < NB2; k += 256) histMat[(size_t)blk * NB2 + k] = h[k];
    if (t < BATCH) batchMat[blk * BATCH + t] = hb[t];
}

// ---------------- K2a: per-bucket exclusive scan over blocks (8-deep ILP) + colT ----------------
__global__ void colscan_kernel(unsigned* __restrict__ histMat, unsigned* __restrict__ totals,
                               unsigned* __restrict__ colT) {
    int k = blockIdx.x * blockDim.x + threadIdx.x;
    if (k >= NB2) return;
    unsigned run = 0;
    for (int b0 = 0; b0 < NBLK; b0 += 8) {
        unsigned v[8];
        #pragma unroll
        for (int u = 0; u < 8; u++) v[u] = histMat[(size_t)(b0+u) * NB2 + k];
        #pragma unroll
        for (int u = 0; u < 8; u++) {
            histMat[(size_t)(b0+u) * NB2 + k] = run;
            colT[(size_t)k * NBLK + (b0+u)]  = run;
            run += v[u];
        }
    }
    totals[k] = run;
}

// ---------------- K2b: batch counts (parallel) + prefixes; single-level bucket scan ----------------
__global__ void scan_kernel(int* __restrict__ ctrl, const int* __restrict__ batchMat,
                            const unsigned* __restrict__ totals, unsigned* __restrict__ recStart) {
    int t = threadIdx.x;
    // batch counts: thread t reads batchMat row t (2x int4), tree-reduce in LDS
    __shared__ int red[256][8];
    {
        const int4* bm = (const int4*)(batchMat + t * BATCH);
        int4 a = bm[0], b = bm[1];
        red[t][0]=a.x; red[t][1]=a.y; red[t][2]=a.z; red[t][3]=a.w;
        red[t][4]=b.x; red[t][5]=b.y; red[t][6]=b.z; red[t][7]=b.w;
    }
    __syncthreads();
    for (int d = 128; d > 0; d >>= 1) {
        if (t < d) {
            #pragma unroll
            for (int b = 0; b < 8; b++) red[t][b] += red[t+d][b];
        }
        __syncthreads();
    }
    if (t == 0) {
        int bs = 0, bsp = 0;
        ctrl[C_BS] = 0; ctrl[C_BSP] = 0;
        for (int b = 0; b < BATCH; b++) {
            int n  = red[0][b];
            ctrl[C_COUNTS + b] = n;
            int np = ((n + G - 1) / G) * G;
            ctrl[C_CP + b] = np;
            bs += n; bsp += np;
            ctrl[C_BS + b + 1]  = bs;
            ctrl[C_BSP + b + 1] = bsp;
        }
    }
    // bucket-totals exclusive scan: thread t owns 9 consecutive entries
    unsigned v[9]; unsigned s = 0;
    int base = t * 9;
    #pragma unroll
    for (int k = 0; k < 9; k++) {
        unsigned x = (base + k < NB2) ? totals[base + k] : 0;
        v[k] = x; s += x;
    }
    __shared__ unsigned sc[256];
    sc[t] = s;
    __syncthreads();
    for (int d = 1; d < 256; d <<= 1) {
        unsigned u = (t >= d) ? sc[t - d] : 0;
        __syncthreads();
        sc[t] += u;
        __syncthreads();
    }
    unsigned run = sc[t] - s;
    #pragma unroll
    for (int k = 0; k < 9; k++) {
        if (base + k < NB2) recStart[base + k] = run;
        run += v[k];
    }
    if (t == 255) recStart[NB2] = run;   // == 2N
}

// ---------------- K3: binning (packed 4B records) + win2flat + fused flat2win ----------------
__global__ void bin_kernel(const int4* __restrict__ coords, int N, int chunk,
                           int Np, int chunkP,
                           const int* __restrict__ ctrl,
                           const unsigned* __restrict__ recStart,
                           const unsigned* __restrict__ histMat,
                           unsigned* __restrict__ rec,
                           int* __restrict__ win2flat,
                           int* __restrict__ f2w) {
    __shared__ unsigned cur[NB2];
    __shared__ int s_bs[BATCH+1], s_bsp[BATCH+1], s_cnt[BATCH], s_cp[BATCH];
    int t = threadIdx.x, blk = blockIdx.x;
    if (t < BATCH)   { s_cnt[t] = ctrl[C_COUNTS+t]; s_cp[t] = ctrl[C_CP+t]; }
    if (t < BATCH+1) { s_bs[t]  = ctrl[C_BS+t];     s_bsp[t] = ctrl[C_BSP+t]; }
    for (int k = t; k < NB2; k += 256)
        cur[k] = recStart[k] + histMat[(size_t)blk * NB2 + k];
    __syncthreads();
    int start = blk * chunk;
    int end   = min(start + chunk, N);
    for (int i = start + t; i < end; i += 256) {
        int4 c = coords[i];
        win2flat[i] = i + (s_bsp[c.x] - s_bs[c.x]);
        unsigned kx, ky;
        keys_from_coord(c, kx, ky);
        unsigned off = (unsigned)(i - start);
        unsigned px = atomicAdd(&cur[kx >> 17], 1u);
        rec[px] = ((kx & 131071u) << 15) | off;
        unsigned py = atomicAdd(&cur[NBUK + (ky >> 17)], 1u);
        rec[py] = ((ky & 131071u) << 15) | off;
    }
    // fused flat2win over this block's slice of [0, Np)
    int pstart = blk * chunkP;
    int pend   = min(pstart + chunkP, Np);
    for (int j = pstart + t; j < pend; j += 256) {
        int b = 0;
        #pragma unroll
        for (int k = 1; k < BATCH; k++) b += (j >= s_bsp[k]);
        int off  = s_bsp[b] - s_bs[b];
        int num  = s_cnt[b], nump = s_cp[b];
        int r    = num % G;
        int tail_start = (num != nump) ? (s_bsp[b+1] - G + r) : s_bsp[b+1];
        int v;
        if (j < tail_start)       v = j - off;
        else if (nump != G)       v = j - G - off;
        else { int tt = j - tail_start; int m = num > 0 ? num : 1; v = s_bs[b] + tt % m; }
        f2w[j] = v;
    }
}

// ---------------- K5: per-bucket LDS bitmap rank + scatter (register-cached recs) ----------------
__global__ void rank_kernel(const unsigned* __restrict__ rec,
                            const unsigned* __restrict__ recStart,
                            const unsigned* __restrict__ colT,
                            int N, int chunk,
                            int* __restrict__ xmap, int* __restrict__ ymap) {
    int b = blockIdx.x;                      // 0..NB2-1
    unsigned start = recStart[b], end = recStart[b+1];
    unsigned sz = end - start;
    int map = (b >= NBUK);
    __shared__ unsigned bits[B_WORDS];       // 16 KB
    __shared__ unsigned prefQ[NQUAD];        // 4 KB
    __shared__ unsigned sc[256];
    __shared__ unsigned col[NBLK + 1];
    __shared__ uint8_t blkOf[MAXBUK];
    int t = threadIdx.x;
    uint4 z = make_uint4(0,0,0,0);
    #pragma unroll
    for (int r = 0; r < 4; r++) ((uint4*)bits)[r*256 + t] = z;
    col[t] = colT[(size_t)b * NBLK + t];
    if (t == 0) col[NBLK] = sz;
    __syncthreads();
    // expand col -> blkOf[pos] = source block
    {
        unsigned lo = col[t], hi = min(col[t + 1], (unsigned)MAXBUK);
        for (unsigned p = lo; p < hi; p++) blkOf[p] = (uint8_t)t;
    }
    bool fast = (sz <= (unsigned)MAXBUK);
    unsigned rl[16];
    if (fast) {
        #pragma unroll
        for (int k = 0; k < 16; k++) {
            unsigned i = start + t + k*256u;
            unsigned r = 0xFFFFFFFFu;
            if (i < end) {
                r = rec[i];
                unsigned local = r >> 15;
                atomicOr(&bits[local >> 5], 1u << (local & 31));
            }
            rl[k] = r;
        }
    } else {
        for (unsigned i = start + t; i < end; i += 256) {
            unsigned local = rec[i] >> 15;
            atomicOr(&bits[local >> 5], 1u << (local & 31));
        }
    }
    __syncthreads();
    // quad sums, lane-contiguous b128 reads
    #pragma unroll
    for (int r = 0; r < 4; r++) {
        uint4 v = ((const uint4*)bits)[r*256 + t];
        prefQ[r*256 + t] = __popc(v.x) + __popc(v.y) + __popc(v.z) + __popc(v.w);
    }
    __syncthreads();
    uint4 q = ((const uint4*)prefQ)[t];
    unsigned tsum = q.x + q.y + q.z + q.w;
    sc[t] = tsum; __syncthreads();
    for (int d = 1; d < 256; d <<= 1) {
        unsigned u = (t >= d) ? sc[t - d] : 0;
        __syncthreads();
        sc[t] += u;
        __syncthreads();
    }
    unsigned e = sc[t] - tsum;
    uint4 pq;
    pq.x = e; pq.y = e + q.x; pq.z = e + q.x + q.y; pq.w = e + q.x + q.y + q.z;
    ((uint4*)prefQ)[t] = pq;
    __syncthreads();
    int* out = map ? ymap : xmap;
    unsigned rankBase = start - (map ? (unsigned)N : 0u);
    if (fast) {
        #pragma unroll
        for (int k = 0; k < 16; k++) {
            unsigned r = rl[k];
            if (r == 0xFFFFFFFFu) continue;
            unsigned local = r >> 15, off = r & 32767u;
            unsigned pos = t + k*256u;
            unsigned blk = blkOf[pos];
            unsigned idx = blk * (unsigned)chunk + off;
            unsigned wd = local >> 5, qi = wd >> 2, j = wd & 3, bt = local & 31;
            uint4 qw = ((const uint4*)bits)[qi];
            unsigned rank = rankBase + prefQ[qi];
            if (j > 0) rank += __popc(qw.x);
            if (j > 1) rank += __popc(qw.y);
            if (j > 2) rank += __popc(qw.z);
            unsigned wj = (j == 0) ? qw.x : (j == 1) ? qw.y : (j == 2) ? qw.z : qw.w;
            rank += __popc(wj & ((1u << bt) - 1u));
            out[rank] = (int)idx;
        }
    } else {
        for (unsigned i = start + t; i < end; i += 256) {
            unsigned r = rec[i];
            unsigned local = r >> 15, off = r & 32767u;
            unsigned pos = i - start;
            unsigned blk;
            if (pos < (unsigned)MAXBUK) blk = blkOf[pos];
            else { blk = NBLK - 1; while (col[blk] > pos) blk--; }
            unsigned idx = blk * (unsigned)chunk + off;
            unsigned wd = local >> 5, qi = wd >> 2, j = wd & 3, bt = local & 31;
            uint4 qw = ((const uint4*)bits)[qi];
            unsigned rank = rankBase + prefQ[qi];
            if (j > 0) rank += __popc(qw.x);
            if (j > 1) rank += __popc(qw.y);
            if (j > 2) rank += __popc(qw.z);
            unsigned wj = (j == 0) ? qw.x : (j == 1) ? qw.y : (j == 2) ? qw.z : qw.w;
            rank += __popc(wj & ((1u << bt) - 1u));
            out[rank] = (int)idx;
        }
    }
}

// ---------------- launch ----------------
extern "C" void kernel_launch(void* const* d_in, const int* in_sizes, int n_in,
                              void* d_out, int out_size, void* d_ws, size_t ws_size,
                              hipStream_t stream) {
    const int* coords = (const int*)d_in[0];
    int N  = in_sizes[0] / 4;
    int Np = out_size - 3 * N;
    int chunk  = (N  + NBLK - 1) / NBLK;   // ~7817, fits 15 bits
    int chunkP = (Np + NBLK - 1) / NBLK;

    char* ws = (char*)d_ws;
    int*      ctrl     = (int*)(ws + 0);              // 256 B
    unsigned* totals   = (unsigned*)(ws + 256);       // 2178*4 -> ends 8968
    unsigned* recStart = (unsigned*)(ws + 8968);      // 2179*4 -> ends 17684
    int*      batchMat = (int*)(ws + 17696);          // 16-aligned; 256*8*4 -> ends 25888
    unsigned* histMat  = (unsigned*)(ws + 25888);     // 256*2178*4 -> ends 2,256,160
    unsigned* colT     = (unsigned*)(ws + 2256160);   // 2178*256*4 -> ends 4,486,432
    unsigned* rec      = (unsigned*)(ws + 4486432);   // 2N*4 B (~16 MB)

    int* out  = (int*)d_out;
    int* f2w  = out;
    int* w2f  = out + Np;
    int* xmap = out + Np + N;
    int* ymap = out + Np + 2*N;

    hist_kernel<<<NBLK, 256, 0, stream>>>((const int4*)coords, N, chunk, histMat, batchMat);
    colscan_kernel<<<(NB2 + 255)/256, 256, 0, stream>>>(histMat, totals, colT);
    scan_kernel<<<1, 256, 0, stream>>>(ctrl, batchMat, totals, recStart);
    bin_kernel<<<NBLK, 256, 0, stream>>>((const int4*)coords, N, chunk, Np, chunkP,
                                         ctrl, recStart, histMat, rec, w2f, f2w);
    rank_kernel<<<NB2, 256, 0, stream>>>(rec, recStart, colT, N, chunk, xmap, ymap);
}